// Round 1
// baseline (864.102 us; speedup 1.0000x reference)
//
#include <hip/hip_runtime.h>
#include <math.h>

// Problem: B=8192, C=128.
// mu_out = softmax(mu_in); Sigma_out = J Sigma J^T, J = diag(p) - p p^T.
// Closed form: Sigma_out[i][l] = p_i * p_l * (Sigma[i][l] - r_i - s_l + q)
//   r = Sigma p, s = p^T Sigma, q = p^T Sigma p.
// Memory-bound: 512 MiB read + 512 MiB write of Sigma. One block per batch.

#define C 128
#define STRIDE 129      // +1 pad: row-dot loop hits 2-way bank aliasing (free)
#define BLOCK 256
#define F4_PER_TILE (C * C / 4)   // 4096

__device__ __forceinline__ float wave_reduce_sum(float v) {
    #pragma unroll
    for (int off = 32; off > 0; off >>= 1) v += __shfl_xor(v, off, 64);
    return v;
}
__device__ __forceinline__ float wave_reduce_max(float v) {
    #pragma unroll
    for (int off = 32; off > 0; off >>= 1) v = fmaxf(v, __shfl_xor(v, off, 64));
    return v;
}

__global__ __launch_bounds__(BLOCK, 1) void jsj_kernel(
    const float* __restrict__ mu_in,
    const float* __restrict__ Sigma_in,
    float* __restrict__ mu_out,
    float* __restrict__ Sigma_out)
{
    const int b    = blockIdx.x;
    const int t    = threadIdx.x;
    const int wave = t >> 6;
    const int lane = t & 63;

    __shared__ float S[C * STRIDE];   // 66048 B
    __shared__ float p[C];
    __shared__ float rs[C];
    __shared__ float ss[C];
    __shared__ float red[8];

    // ---- issue the Sigma tile loads first (16 x float4 per thread, coalesced)
    const float4* Sg = (const float4*)(Sigma_in + (size_t)b * (C * C));
    float4 v[16];
    #pragma unroll
    for (int it = 0; it < 16; ++it)
        v[it] = Sg[t + it * BLOCK];

    // ---- softmax over mu row while the global loads are in flight
    float x = (t < C) ? mu_in[b * C + t] : -INFINITY;
    float m = wave_reduce_max(x);
    if (lane == 0) red[wave] = m;
    __syncthreads();
    m = fmaxf(fmaxf(red[0], red[1]), fmaxf(red[2], red[3]));
    float e = (t < C) ? expf(x - m) : 0.0f;
    float es = wave_reduce_sum(e);
    if (lane == 0) red[4 + wave] = es;   // disjoint slots from red[0..3]
    __syncthreads();
    float denom = red[4] + red[5] + red[6] + red[7];
    float pt = e / denom;
    if (t < C) { p[t] = pt; mu_out[b * C + t] = pt; }

    // ---- stage Sigma into padded LDS
    #pragma unroll
    for (int it = 0; it < 16; ++it) {
        int f   = t + it * BLOCK;
        int row = f >> 5;              // 32 float4 per row
        int col = (f & 31) << 2;
        float* dst = &S[row * STRIDE + col];
        dst[0] = v[it].x; dst[1] = v[it].y; dst[2] = v[it].z; dst[3] = v[it].w;
    }
    __syncthreads();

    // ---- r (threads 0..127) and s (threads 128..255) concurrently
    float acc = 0.0f;
    if (t < C) {
        const float* row = &S[t * STRIDE];     // banks (t+k)%32: 2-way, free
        #pragma unroll 8
        for (int k = 0; k < C; ++k) acc += row[k] * p[k];
        rs[t] = acc;
    } else {
        const int l = t - C;
        #pragma unroll 8
        for (int j = 0; j < C; ++j) acc += p[j] * S[j * STRIDE + l]; // contiguous lanes
        ss[l] = acc;
    }
    __syncthreads();

    // ---- q = sum_i r_i p_i (block reduce)
    float val = (t < C) ? rs[t] * p[t] : 0.0f;
    float wq = wave_reduce_sum(val);
    if (lane == 0) red[wave] = wq;
    __syncthreads();
    const float q = red[0] + red[1] + red[2] + red[3];

    // ---- epilogue: Sigma_out[i][l] = p_i p_l (S[i][l] - ss[l] - rs[i] + q)
    float4* Og = (float4*)(Sigma_out + (size_t)b * (C * C));
    #pragma unroll
    for (int it = 0; it < 16; ++it) {
        int f    = t + it * BLOCK;
        int row  = f >> 5;
        int col  = (f & 31) << 2;
        float pi   = p[row];
        float base = q - rs[row];
        const float* srow = &S[row * STRIDE + col];
        float4 o;
        o.x = pi * p[col + 0] * (srow[0] - ss[col + 0] + base);
        o.y = pi * p[col + 1] * (srow[1] - ss[col + 1] + base);
        o.z = pi * p[col + 2] * (srow[2] - ss[col + 2] + base);
        o.w = pi * p[col + 3] * (srow[3] - ss[col + 3] + base);
        Og[f] = o;
    }
}

extern "C" void kernel_launch(void* const* d_in, const int* in_sizes, int n_in,
                              void* d_out, int out_size, void* d_ws, size_t ws_size,
                              hipStream_t stream) {
    const float* mu_in    = (const float*)d_in[0];
    const float* Sigma_in = (const float*)d_in[1];
    const int B = in_sizes[0] / C;          // 8192

    float* mu_out    = (float*)d_out;             // B*C floats
    float* Sigma_out = (float*)d_out + (size_t)B * C;  // B*C*C floats

    jsj_kernel<<<B, BLOCK, 0, stream>>>(mu_in, Sigma_in, mu_out, Sigma_out);
}